// Round 2
// baseline (168.075 us; speedup 1.0000x reference)
//
#include <hip/hip_runtime.h>
#include <stdint.h>

#define Bq 4
#define Sq 4096
#define DIN 512
#define Uq 128
#define Mq (Bq * Sq)

typedef __attribute__((ext_vector_type(8))) _Float16 f16x8;
typedef __attribute__((ext_vector_type(4))) float f32x4;

__device__ __forceinline__ unsigned short f2h(float f) {
  union { _Float16 h; unsigned short u; } v;
  v.h = (_Float16)f;
  return v.u;
}

// ---------------- W transpose: W[512][128] f32 -> Wt[128][512] fp16 ----------------
__global__ __launch_bounds__(256) void wt_kernel(const float* __restrict__ Wqp,
                                                 const float* __restrict__ Wkp,
                                                 const float* __restrict__ Wvp,
                                                 unsigned short* __restrict__ wt) {
  int idx = blockIdx.x * 256 + threadIdx.x;   // 0 .. 3*65536-1
  int z = idx >> 16, r = idx & 65535;
  int n = r >> 9, k = r & 511;
  const float* W = (z == 0) ? Wqp : ((z == 1) ? Wkp : Wvp);
  wt[idx] = f2h(W[k * Uq + n]);
}

// ---------------- fused QKV projection + ReLU -> fp16 (q,k row-major; v transposed) ----
__global__ __launch_bounds__(256) void proj_kernel(const float* __restrict__ X,
                                                   const unsigned short* __restrict__ Wt,
                                                   const float* __restrict__ bqp,
                                                   const float* __restrict__ bkp,
                                                   const float* __restrict__ bvp,
                                                   unsigned short* __restrict__ qkv) {
  const int z = blockIdx.y;
  const int mbase = blockIdx.x * 64;
  const int tid = threadIdx.x;
  const int wid = tid >> 6, lane = tid & 63;
  const int lo = lane & 15, g = lane >> 4;

  __shared__ __align__(16) unsigned short xt[64][40];   // 64 rows x 32 fp16 (+pad)

  const unsigned short* Wz = Wt + z * 65536;            // Wt_z[n][k], row = 512 fp16
  const float* bias = (z == 0) ? bqp : ((z == 1) ? bkp : bvp);

  f32x4 acc[8];
#pragma unroll
  for (int f = 0; f < 8; ++f) acc[f] = (f32x4){0.f, 0.f, 0.f, 0.f};

  for (int step = 0; step < 16; ++step) {
    const int k0 = step * 32;
    {   // stage X tile 64x32 f32 -> fp16, coalesced
      const int row = tid >> 2, c = (tid & 3) * 8;
      const float* src = X + (size_t)(mbase + row) * DIN + k0 + c;
      float4 v0 = *(const float4*)src;
      float4 v1 = *(const float4*)(src + 4);
      union { unsigned short u[8]; uint4 v; } pk;
      pk.u[0] = f2h(v0.x); pk.u[1] = f2h(v0.y); pk.u[2] = f2h(v0.z); pk.u[3] = f2h(v0.w);
      pk.u[4] = f2h(v1.x); pk.u[5] = f2h(v1.y); pk.u[6] = f2h(v1.z); pk.u[7] = f2h(v1.w);
      *(uint4*)(&xt[row][c]) = pk.v;
    }
    __syncthreads();
    // A frag: X[mbase+16w+lo][k0 + 8g + j]
    f16x8 a = *(const f16x8*)(&xt[16 * wid + lo][8 * g]);
#pragma unroll
    for (int f = 0; f < 8; ++f) {
      // B frag: W[k0+8g+j][16f+lo] = Wt[16f+lo][k0+8g+j]  (contiguous 16B, L2-hot)
      f16x8 bfr = *(const f16x8*)(Wz + (16 * f + lo) * 512 + k0 + 8 * g);
      acc[f] = __builtin_amdgcn_mfma_f32_16x16x32_f16(a, bfr, acc[f], 0, 0, 0);
    }
    __syncthreads();
  }

  // C/D layout: col = lane&15 (n), row = 4*(lane>>4)+reg (m)
  if (z < 2) {
    unsigned short* dst = qkv + (size_t)z * Mq * Uq;
#pragma unroll
    for (int f = 0; f < 8; ++f) {
      const int n = 16 * f + lo;
      const float bb = bias[n];
#pragma unroll
      for (int r = 0; r < 4; ++r) {
        const int m = mbase + 16 * wid + 4 * g + r;
        dst[(size_t)m * Uq + n] = f2h(fmaxf(acc[f][r] + bb, 0.f));
      }
    }
  } else {
    // v stored transposed: vT[batch][n][s]  (so PV B-frags are contiguous reads)
    unsigned short* vT = qkv + (size_t)2 * Mq * Uq;
    const int m0 = mbase + 16 * wid + 4 * g;
    const int bb_ = m0 >> 12, s0 = m0 & (Sq - 1);
#pragma unroll
    for (int f = 0; f < 8; ++f) {
      const int n = 16 * f + lo;
      const float bb = bias[n];
      ushort4 pv = make_ushort4(f2h(fmaxf(acc[f][0] + bb, 0.f)),
                                f2h(fmaxf(acc[f][1] + bb, 0.f)),
                                f2h(fmaxf(acc[f][2] + bb, 0.f)),
                                f2h(fmaxf(acc[f][3] + bb, 0.f)));
      *(ushort4*)(vT + (size_t)bb_ * Uq * Sq + (size_t)n * Sq + s0) = pv;
    }
  }
}

// ---------------- flash attention: softmax(Q K^T) V ----------------
// block = 128 threads (2 waves), each wave owns 16 q-rows; KBLK = 64.
__global__ __launch_bounds__(128) void attn_kernel(const unsigned short* __restrict__ qkv,
                                                   float* __restrict__ out) {
  const int bid = blockIdx.x;                       // 512 blocks
  const int w = (bid & 7) * 64 + (bid >> 3);        // XCD-contiguous work mapping
  const int b = w >> 7;
  const int qt = w & 127;
  const int tid = threadIdx.x;
  const int wid = tid >> 6, lane = tid & 63;
  const int lo = lane & 15, g = lane >> 4;

  const unsigned short* qp = qkv;
  const unsigned short* kbase = qkv + (size_t)Mq * Uq + (size_t)b * Sq * Uq;
  const unsigned short* vbase = qkv + (size_t)2 * Mq * Uq + (size_t)b * Uq * Sq;

  __shared__ __align__(16) unsigned char kt[64 * 256];        // K tile, XOR-swizzled rows
  __shared__ __align__(16) unsigned char vt[128 * 144];       // vT tile, padded rows
  __shared__ __align__(16) unsigned char plds[2][16 * 144];   // per-wave P round-trip

  // Q frags (B operand of swapped QK^T): Q[qrow][32t + 8g + j], held in regs
  const int qrow = b * Sq + qt * 32 + wid * 16 + lo;
  f16x8 qf[4];
#pragma unroll
  for (int t = 0; t < 4; ++t)
    qf[t] = *(const f16x8*)(qp + (size_t)qrow * Uq + 32 * t + 8 * g);

  f32x4 acc[8];
#pragma unroll
  for (int f = 0; f < 8; ++f) acc[f] = (f32x4){0.f, 0.f, 0.f, 0.f};
  float m_run = -1e30f, l_run = 0.f;

  for (int it = 0; it < Sq / 64; ++it) {
    const int kv0 = it * 64;
    // ---- stage K tile (64x128 fp16, swizzled) + V tile (128 n x 64 kv) ----
#pragma unroll
    for (int i = 0; i < 8; ++i) {
      const int c = tid + 128 * i;              // 0..1023 16B-chunks
      const int row = c >> 4, gg = c & 15;
      uint4 d = *(const uint4*)(kbase + (size_t)(kv0 + row) * Uq + gg * 8);
      *(uint4*)(&kt[row * 256 + ((gg ^ (row & 7)) << 4)]) = d;
    }
#pragma unroll
    for (int i = 0; i < 8; ++i) {
      const int c = tid + 128 * i;
      const int n = c >> 3, gg = c & 7;
      uint4 d = *(const uint4*)(vbase + (size_t)n * Sq + kv0 + gg * 8);
      *(uint4*)(&vt[n * 144 + gg * 16]) = d;
    }
    __syncthreads();

    // ---- QK^T (swapped): D[kv][q], lane owns q = lo, kv = 16h + 4g + r ----
    f32x4 sf[4];
#pragma unroll
    for (int h = 0; h < 4; ++h) {
      sf[h] = (f32x4){0.f, 0.f, 0.f, 0.f};
      const int row = 16 * h + lo;
#pragma unroll
      for (int t = 0; t < 4; ++t) {
        f16x8 a = *(const f16x8*)(&kt[row * 256 + ((64 * t + 16 * g) ^ ((lo & 7) << 4))]);
        sf[h] = __builtin_amdgcn_mfma_f32_16x16x32_f16(a, qf[t], sf[h], 0, 0, 0);
      }
    }

    // ---- online softmax (row q = lo, values spread over 4 lanes via g) ----
    float tmax = -1e30f;
#pragma unroll
    for (int h = 0; h < 4; ++h)
#pragma unroll
      for (int r = 0; r < 4; ++r) tmax = fmaxf(tmax, sf[h][r]);
    tmax = fmaxf(tmax, __shfl_xor(tmax, 16));
    tmax = fmaxf(tmax, __shfl_xor(tmax, 32));

    if (__any(tmax > m_run)) {     // rescale only when some row's max grew
      const float m_new = fmaxf(m_run, tmax);
      const float scale = __expf(m_run - m_new);
#pragma unroll
      for (int r = 0; r < 4; ++r) {
        const float sc = __shfl(scale, 4 * g + r);   // acc rows are q = 4g+r
#pragma unroll
        for (int f = 0; f < 8; ++f) acc[f][r] *= sc;
      }
      l_run *= scale;
      m_run = m_new;
    }

    float psum = 0.f;
    unsigned short pb[16];
#pragma unroll
    for (int h = 0; h < 4; ++h)
#pragma unroll
      for (int r = 0; r < 4; ++r) {
        const float pv = __expf(sf[h][r] - m_run);
        psum += pv;
        pb[4 * h + r] = f2h(pv);
      }
    psum += __shfl_xor(psum, 16);
    psum += __shfl_xor(psum, 32);
    l_run += psum;

    // ---- P re-fragment through per-wave LDS ----
#pragma unroll
    for (int h = 0; h < 4; ++h) {
      ushort4 p4 = make_ushort4(pb[4 * h + 0], pb[4 * h + 1], pb[4 * h + 2], pb[4 * h + 3]);
      *(ushort4*)(&plds[wid][lo * 144 + 32 * h + 8 * g]) = p4;   // [q=lo][kv=16h+4g..+3]
    }

    // ---- PV: acc[q=4g+r][n] += P[q][kv] * V[kv][n] ----
#pragma unroll
    for (int s = 0; s < 2; ++s) {
      f16x8 pa = *(const f16x8*)(&plds[wid][lo * 144 + 64 * s + 16 * g]);
#pragma unroll
      for (int f = 0; f < 8; ++f) {
        f16x8 bv = *(const f16x8*)(&vt[(16 * f + lo) * 144 + 64 * s + 16 * g]);
        acc[f] = __builtin_amdgcn_mfma_f32_16x16x32_f16(pa, bv, acc[f], 0, 0, 0);
      }
    }
    __syncthreads();
  }

  // ---- normalize + store ----
  float linv[4];
#pragma unroll
  for (int r = 0; r < 4; ++r) linv[r] = 1.f / __shfl(l_run, 4 * g + r);

  const int orow0 = b * Sq + qt * 32 + wid * 16 + 4 * g;
#pragma unroll
  for (int f = 0; f < 8; ++f) {
    const int n = 16 * f + lo;
#pragma unroll
    for (int r = 0; r < 4; ++r)
      out[(size_t)(orow0 + r) * Uq + n] = acc[f][r] * linv[r];
  }
}

extern "C" void kernel_launch(void* const* d_in, const int* in_sizes, int n_in,
                              void* d_out, int out_size, void* d_ws, size_t ws_size,
                              hipStream_t stream) {
  const float* X  = (const float*)d_in[0];
  const float* Wqp = (const float*)d_in[1];
  const float* bqp = (const float*)d_in[2];
  const float* Wkp = (const float*)d_in[3];
  const float* bkp = (const float*)d_in[4];
  const float* Wvp = (const float*)d_in[5];
  const float* bvp = (const float*)d_in[6];
  float* out = (float*)d_out;

  unsigned short* qkv = (unsigned short*)d_ws;            // q(4MB) k(4MB) vT(4MB) fp16
  unsigned short* wt  = qkv + (size_t)3 * Mq * Uq;        // Wt: 3 x [128][512] fp16

  wt_kernel<<<768, 256, 0, stream>>>(Wqp, Wkp, Wvp, wt);
  proj_kernel<<<dim3(Mq / 64, 3), 256, 0, stream>>>(X, wt, bqp, bkp, bvp, qkv);
  attn_kernel<<<512, 128, 0, stream>>>(qkv, out);
}